// Round 1
// baseline (377.503 us; speedup 1.0000x reference)
//
#include <hip/hip_runtime.h>

typedef _Float16 f16;
typedef _Float16 half8 __attribute__((ext_vector_type(8)));
typedef _Float16 half4 __attribute__((ext_vector_type(4)));
typedef float float4_ __attribute__((ext_vector_type(4)));

#define MFMA16(a, b, c) __builtin_amdgcn_mfma_f32_16x16x32_f16(a, b, c, 0, 0, 0)

__device__ __forceinline__ void gld_lds16(const void* g, void* l) {
    __builtin_amdgcn_global_load_lds(
        (const __attribute__((address_space(1))) void*)g,
        (__attribute__((address_space(3))) void*)l, 16, 0, 0);
}

// ---------------- cast fp32 -> fp16 (optionally scale first `qboundary` elems)
__global__ void cast_kernel(const float* __restrict__ in, f16* __restrict__ out,
                            int n, int qboundary, float qscale) {
    int i = (blockIdx.x * blockDim.x + threadIdx.x) * 4;
    if (i >= n) return;
    float4_ v = *(const float4_*)(in + i);
    float sc = (i < qboundary) ? qscale : 1.0f;
    half4 h;
    h[0] = (f16)(v[0] * sc);
    h[1] = (f16)(v[1] * sc);
    h[2] = (f16)(v[2] * sc);
    h[3] = (f16)(v[3] * sc);
    *(half4*)(out + i) = h;
}

// ---------------- QKV GEMM: [8192,1024] x [3072,1024]^T, scatter to q/k/v [B,H,N,64]
__global__ __launch_bounds__(256, 2)
void qkv_gemm(const f16* __restrict__ X, const f16* __restrict__ W,
              f16* __restrict__ Q, f16* __restrict__ Kq, f16* __restrict__ V) {
    const int K = 1024;
    __shared__ __align__(16) f16 sA[128 * 64];
    __shared__ __align__(16) f16 sB[128 * 64];
    int tid = threadIdx.x;
    int lane = tid & 63, wave = tid >> 6;
    int wm = wave >> 1, wn = wave & 1;
    int l15 = lane & 15, quad = lane >> 4;
    int rowBase = blockIdx.y * 128;  // token index
    int colBase = blockIdx.x * 128;  // qkv dim index

    float4_ acc[4][4] = {};

    for (int k0 = 0; k0 < K; k0 += 64) {
        for (int i = 0; i < 4; ++i) {
            int seg = wave * 4 + i;
            int e = (seg * 64 + lane) * 8;
            int r = e >> 6, c = e & 63;
            gld_lds16(X + (size_t)(rowBase + r) * K + k0 + c, sA + seg * 512);
            gld_lds16(W + (size_t)(colBase + r) * K + k0 + c, sB + seg * 512);
        }
        __syncthreads();
        for (int ks = 0; ks < 2; ++ks) {
            half8 a[4], b[4];
            for (int mt = 0; mt < 4; ++mt)
                a[mt] = *(const half8*)&sA[(wm * 64 + mt * 16 + l15) * 64 + ks * 32 + quad * 8];
            for (int nt = 0; nt < 4; ++nt)
                b[nt] = *(const half8*)&sB[(wn * 64 + nt * 16 + l15) * 64 + ks * 32 + quad * 8];
            for (int mt = 0; mt < 4; ++mt)
                for (int nt = 0; nt < 4; ++nt)
                    acc[mt][nt] = MFMA16(a[mt], b[nt], acc[mt][nt]);
        }
        __syncthreads();
    }

    for (int mt = 0; mt < 4; ++mt) {
        int m0 = rowBase + wm * 64 + mt * 16 + quad * 4;
        for (int nt = 0; nt < 4; ++nt) {
            int d = colBase + wn * 64 + nt * 16 + l15;
            int part = d >> 10;
            int h = (d >> 6) & 15;
            int hd = d & 63;
            f16* dst = (part == 0) ? Q : (part == 1) ? Kq : V;
            for (int r = 0; r < 4; ++r) {
                int m = m0 + r;
                int b = m >> 11, n = m & 2047;
                dst[(size_t)((b * 16 + h) * 2048 + n) * 64 + hd] = (f16)acc[mt][nt][r];
            }
        }
    }
}

// ---------------- Flash attention: per (b,h), 128 q-rows per block, 64-key tiles
// This round: ones-MFMA row sums, defer-max (THR=8, log2 domain), K/V register
// prefetch for next tile, double-buffered Vt with ONE barrier per tile.
__global__ __launch_bounds__(256, 2)
void attn_kernel(const f16* __restrict__ Q, const f16* __restrict__ Kk,
                 const f16* __restrict__ V, f16* __restrict__ O) {
    const int bh = blockIdx.y;
    const int qt = blockIdx.x;
    const f16* Qb = Q + (size_t)bh * 2048 * 64;
    const f16* Kb = Kk + (size_t)bh * 2048 * 64;
    const f16* Vb = V + (size_t)bh * 2048 * 64;
    int tid = threadIdx.x, lane = tid & 63, wave = tid >> 6;
    int l15 = lane & 15, quad = lane >> 4;

    __shared__ __align__(16) f16 Vt[2][64 * 72];   // V^T [hd][key], double-buffered
    __shared__ __align__(16) f16 Pl[4][32 * 72];   // per-wave P [row][key]

    int qrow = qt * 128 + wave * 32;
    half8 aQ[2][2];
#pragma unroll
    for (int mt = 0; mt < 2; ++mt)
#pragma unroll
        for (int kc = 0; kc < 2; ++kc)
            aQ[mt][kc] = *(const half8*)(Qb + (size_t)(qrow + mt * 16 + l15) * 64 + kc * 32 + quad * 8);

    float4_ oacc[2][4] = {};
    float4_ lacc[2] = {};            // row sums via ones-MFMA
    float mrow[2][4];
#pragma unroll
    for (int mt = 0; mt < 2; ++mt)
#pragma unroll
        for (int r = 0; r < 4; ++r) mrow[mt][r] = -1e30f;

    f16* Pw = &Pl[wave][0];

    half8 vone;
#pragma unroll
    for (int j = 0; j < 8; ++j) vone[j] = (f16)1.0f;

    // prologue: tile 0 K/V into regs; stage Vt[0]
    half8 bK[2][4], v0, v1;
    {
        const f16* vsrc = Vb + (size_t)lane * 64 + wave * 16;
        v0 = *(const half8*)(vsrc);
        v1 = *(const half8*)(vsrc + 8);
#pragma unroll
        for (int kc = 0; kc < 2; ++kc)
#pragma unroll
            for (int nt = 0; nt < 4; ++nt)
                bK[kc][nt] = *(const half8*)(Kb + (size_t)(nt * 16 + l15) * 64 + kc * 32 + quad * 8);
#pragma unroll
        for (int j = 0; j < 8; ++j) {
            Vt[0][(wave * 16 + j) * 72 + lane] = v0[j];
            Vt[0][(wave * 16 + 8 + j) * 72 + lane] = v1[j];
        }
    }

    for (int it = 0; it < 32; ++it) {
        int buf = it & 1;
        __syncthreads();  // Vt[buf] staged by all waves; prior reads of Vt[buf^1] done
        // S = Q K^T
        float4_ s[2][4] = {};
#pragma unroll
        for (int kc = 0; kc < 2; ++kc)
#pragma unroll
            for (int mt = 0; mt < 2; ++mt)
#pragma unroll
                for (int nt = 0; nt < 4; ++nt)
                    s[mt][nt] = MFMA16(aQ[mt][kc], bK[kc][nt], s[mt][nt]);
        // prefetch next tile K/V into regs (latency hides under softmax + PV)
        half8 bKn[2][4], v0n, v1n;
        if (it < 31) {
            int t1 = (it + 1) * 64;
            const f16* vsrc = Vb + (size_t)(t1 + lane) * 64 + wave * 16;
            v0n = *(const half8*)(vsrc);
            v1n = *(const half8*)(vsrc + 8);
#pragma unroll
            for (int kc = 0; kc < 2; ++kc)
#pragma unroll
                for (int nt = 0; nt < 4; ++nt)
                    bKn[kc][nt] = *(const half8*)(Kb + (size_t)(t1 + nt * 16 + l15) * 64 + kc * 32 + quad * 8);
        }
        // row max (cross-quad shuffle reduce; 4 rows per pass in parallel across quads)
        float mx[2][4];
        int grow = 0;
#pragma unroll
        for (int mt = 0; mt < 2; ++mt)
#pragma unroll
            for (int r = 0; r < 4; ++r) {
                float m = fmaxf(fmaxf(s[mt][0][r], s[mt][1][r]),
                                fmaxf(s[mt][2][r], s[mt][3][r]));
                for (int off = 1; off < 16; off <<= 1)
                    m = fmaxf(m, __shfl_xor(m, off, 64));
                mx[mt][r] = m;
                grow |= (m > mrow[mt][r] + 8.f) ? 1 : 0;
            }
        // defer-max: only rescale when some row's max grew by > 8 (P bounded by 2^8)
        if (__any(grow)) {
#pragma unroll
            for (int mt = 0; mt < 2; ++mt)
#pragma unroll
                for (int r = 0; r < 4; ++r) {
                    float mnew = fmaxf(mrow[mt][r], mx[mt][r]);
                    float alpha = exp2f(mrow[mt][r] - mnew);
                    mrow[mt][r] = mnew;
#pragma unroll
                    for (int ht = 0; ht < 4; ++ht) oacc[mt][ht][r] *= alpha;
                    lacc[mt][r] *= alpha;
                }
        }
        // P = exp2(s - m) -> per-wave LDS (row-major [row][key])
#pragma unroll
        for (int mt = 0; mt < 2; ++mt)
#pragma unroll
            for (int nt = 0; nt < 4; ++nt)
#pragma unroll
                for (int r = 0; r < 4; ++r) {
                    float p = exp2f(s[mt][nt][r] - mrow[mt][r]);
                    Pw[(mt * 16 + quad * 4 + r) * 72 + nt * 16 + l15] = (f16)p;
                }
        // O += P V ; l += P 1   (P is wave-private: compiler's lgkmcnt ordering suffices)
#pragma unroll
        for (int kc = 0; kc < 2; ++kc) {
            half8 aP[2], bV[4];
#pragma unroll
            for (int mt = 0; mt < 2; ++mt)
                aP[mt] = *(const half8*)&Pw[(mt * 16 + l15) * 72 + kc * 32 + quad * 8];
#pragma unroll
            for (int ht = 0; ht < 4; ++ht)
                bV[ht] = *(const half8*)&Vt[buf][(ht * 16 + l15) * 72 + kc * 32 + quad * 8];
#pragma unroll
            for (int mt = 0; mt < 2; ++mt) {
#pragma unroll
                for (int ht = 0; ht < 4; ++ht)
                    oacc[mt][ht] = MFMA16(aP[mt], bV[ht], oacc[mt][ht]);
                lacc[mt] = MFMA16(aP[mt], vone, lacc[mt]);
            }
        }
        // stage next Vt into the other buffer; rotate K prefetch regs
        if (it < 31) {
#pragma unroll
            for (int j = 0; j < 8; ++j) {
                Vt[buf ^ 1][(wave * 16 + j) * 72 + lane] = v0n[j];
                Vt[buf ^ 1][(wave * 16 + 8 + j) * 72 + lane] = v1n[j];
            }
#pragma unroll
            for (int kc = 0; kc < 2; ++kc)
#pragma unroll
                for (int nt = 0; nt < 4; ++nt)
                    bK[kc][nt] = bKn[kc][nt];
        }
    }
    // epilogue: O / l -> attn_out [B,N,C] fp16
    int b = bh >> 4, h = bh & 15;
#pragma unroll
    for (int mt = 0; mt < 2; ++mt) {
#pragma unroll
        for (int r = 0; r < 4; ++r) {
            float inv = 1.f / lacc[mt][r];
            int n = qrow + mt * 16 + quad * 4 + r;
#pragma unroll
            for (int ht = 0; ht < 4; ++ht) {
                int c = h * 64 + ht * 16 + l15;
                O[(size_t)(b * 2048 + n) * 1024 + c] = (f16)(oacc[mt][ht][r] * inv);
            }
        }
    }
}

// ---------------- Proj GEMM: [8192,1024] x [1024,1024]^T + bias -> fp32 out
__global__ __launch_bounds__(256, 2)
void proj_gemm(const f16* __restrict__ A, const f16* __restrict__ W,
               const float* __restrict__ bias, float* __restrict__ out) {
    const int K = 1024;
    __shared__ __align__(16) f16 sA[128 * 64];
    __shared__ __align__(16) f16 sB[128 * 64];
    int tid = threadIdx.x;
    int lane = tid & 63, wave = tid >> 6;
    int wm = wave >> 1, wn = wave & 1;
    int l15 = lane & 15, quad = lane >> 4;
    int rowBase = blockIdx.y * 128;
    int colBase = blockIdx.x * 128;

    float4_ acc[4][4] = {};

    for (int k0 = 0; k0 < K; k0 += 64) {
        for (int i = 0; i < 4; ++i) {
            int seg = wave * 4 + i;
            int e = (seg * 64 + lane) * 8;
            int r = e >> 6, c = e & 63;
            gld_lds16(A + (size_t)(rowBase + r) * K + k0 + c, sA + seg * 512);
            gld_lds16(W + (size_t)(colBase + r) * K + k0 + c, sB + seg * 512);
        }
        __syncthreads();
        for (int ks = 0; ks < 2; ++ks) {
            half8 a[4], b[4];
            for (int mt = 0; mt < 4; ++mt)
                a[mt] = *(const half8*)&sA[(wm * 64 + mt * 16 + l15) * 64 + ks * 32 + quad * 8];
            for (int nt = 0; nt < 4; ++nt)
                b[nt] = *(const half8*)&sB[(wn * 64 + nt * 16 + l15) * 64 + ks * 32 + quad * 8];
            for (int mt = 0; mt < 4; ++mt)
                for (int nt = 0; nt < 4; ++nt)
                    acc[mt][nt] = MFMA16(a[mt], b[nt], acc[mt][nt]);
        }
        __syncthreads();
    }

    for (int mt = 0; mt < 4; ++mt) {
        int m0 = rowBase + wm * 64 + mt * 16 + quad * 4;
        for (int nt = 0; nt < 4; ++nt) {
            int d = colBase + wn * 64 + nt * 16 + l15;
            float bv = bias[d];
            for (int r = 0; r < 4; ++r) {
                int m = m0 + r;
                out[(size_t)m * 1024 + d] = acc[mt][nt][r] + bv;
            }
        }
    }
}

extern "C" void kernel_launch(void* const* d_in, const int* in_sizes, int n_in,
                              void* d_out, int out_size, void* d_ws, size_t ws_size,
                              hipStream_t stream) {
    const float* x     = (const float*)d_in[0];
    const float* Wqkv  = (const float*)d_in[1];
    const float* Wproj = (const float*)d_in[2];
    const float* bproj = (const float*)d_in[3];
    float* out = (float*)d_out;

    f16* ws     = (f16*)d_ws;
    f16* xb     = ws;                    // 8388608
    f16* wqkvb  = xb + 8388608;          // 3145728
    f16* wprojb = wqkvb + 3145728;       // 1048576
    f16* q      = wprojb + 1048576;      // 8388608  [B,H,N,64]
    f16* k      = q + 8388608;           // 8388608
    f16* v      = k + 8388608;           // 8388608
    f16* ao     = v + 8388608;           // 8388608  [B,N,C]

    // qkv scale: 1/sqrt(64) * log2(e) folded into Q rows of W_qkv
    const float qscale = 0.125f * 1.4426950408889634f;

    cast_kernel<<<8192, 256, 0, stream>>>(x, xb, 8388608, 0, 1.f);
    cast_kernel<<<3072, 256, 0, stream>>>(Wqkv, wqkvb, 3145728, 1048576, qscale);
    cast_kernel<<<1024, 256, 0, stream>>>(Wproj, wprojb, 1048576, 0, 1.f);

    qkv_gemm<<<dim3(24, 64), 256, 0, stream>>>(xb, wqkvb, q, k, v);
    attn_kernel<<<dim3(16, 64), 256, 0, stream>>>(q, k, v, ao);
    proj_gemm<<<dim3(8, 64), 256, 0, stream>>>(ao, wprojb, bproj, out);
}

// Round 4
// 343.343 us; speedup vs baseline: 1.0995x; 1.0995x over previous
//
#include <hip/hip_runtime.h>

typedef _Float16 f16;
typedef _Float16 half8 __attribute__((ext_vector_type(8)));
typedef _Float16 half4 __attribute__((ext_vector_type(4)));
typedef __fp16 fp16x2 __attribute__((ext_vector_type(2)));
typedef float float4_ __attribute__((ext_vector_type(4)));
typedef float f32x16 __attribute__((ext_vector_type(16)));
typedef unsigned int uint2_ __attribute__((ext_vector_type(2)));

#define MFMA16(a, b, c) __builtin_amdgcn_mfma_f32_16x16x32_f16(a, b, c, 0, 0, 0)
#define MFMA32(a, b, c) __builtin_amdgcn_mfma_f32_32x32x16_f16(a, b, c, 0, 0, 0)

__device__ __forceinline__ void gld_lds16(const void* g, void* l) {
    __builtin_amdgcn_global_load_lds(
        (const __attribute__((address_space(1))) void*)g,
        (__attribute__((address_space(3))) void*)l, 16, 0, 0);
}

__device__ __forceinline__ unsigned pkrtz(float a, float b) {
    union { fp16x2 h; unsigned u; } c;
    c.h = __builtin_amdgcn_cvt_pkrtz(a, b);
    return c.u;
}

// ---------------- cast fp32 -> fp16 (optionally scale first `qboundary` elems)
__global__ void cast_kernel(const float* __restrict__ in, f16* __restrict__ out,
                            int n, int qboundary, float qscale) {
    int i = (blockIdx.x * blockDim.x + threadIdx.x) * 4;
    if (i >= n) return;
    float4_ v = *(const float4_*)(in + i);
    float sc = (i < qboundary) ? qscale : 1.0f;
    half4 h;
    h[0] = (f16)(v[0] * sc);
    h[1] = (f16)(v[1] * sc);
    h[2] = (f16)(v[2] * sc);
    h[3] = (f16)(v[3] * sc);
    *(half4*)(out + i) = h;
}

// ---------------- QKV GEMM: [8192,1024] x [3072,1024]^T, scatter to q/k/v [B,H,N,64]
__global__ __launch_bounds__(256, 2)
void qkv_gemm(const f16* __restrict__ X, const f16* __restrict__ W,
              f16* __restrict__ Q, f16* __restrict__ Kq, f16* __restrict__ V) {
    const int K = 1024;
    __shared__ __align__(16) f16 sA[128 * 64];
    __shared__ __align__(16) f16 sB[128 * 64];
    int tid = threadIdx.x;
    int lane = tid & 63, wave = tid >> 6;
    int wm = wave >> 1, wn = wave & 1;
    int l15 = lane & 15, quad = lane >> 4;
    int rowBase = blockIdx.y * 128;  // token index
    int colBase = blockIdx.x * 128;  // qkv dim index

    float4_ acc[4][4] = {};

    for (int k0 = 0; k0 < K; k0 += 64) {
        for (int i = 0; i < 4; ++i) {
            int seg = wave * 4 + i;
            int e = (seg * 64 + lane) * 8;
            int r = e >> 6, c = e & 63;
            gld_lds16(X + (size_t)(rowBase + r) * K + k0 + c, sA + seg * 512);
            gld_lds16(W + (size_t)(colBase + r) * K + k0 + c, sB + seg * 512);
        }
        __syncthreads();
        for (int ks = 0; ks < 2; ++ks) {
            half8 a[4], b[4];
            for (int mt = 0; mt < 4; ++mt)
                a[mt] = *(const half8*)&sA[(wm * 64 + mt * 16 + l15) * 64 + ks * 32 + quad * 8];
            for (int nt = 0; nt < 4; ++nt)
                b[nt] = *(const half8*)&sB[(wn * 64 + nt * 16 + l15) * 64 + ks * 32 + quad * 8];
            for (int mt = 0; mt < 4; ++mt)
                for (int nt = 0; nt < 4; ++nt)
                    acc[mt][nt] = MFMA16(a[mt], b[nt], acc[mt][nt]);
        }
        __syncthreads();
    }

    for (int mt = 0; mt < 4; ++mt) {
        int m0 = rowBase + wm * 64 + mt * 16 + quad * 4;
        for (int nt = 0; nt < 4; ++nt) {
            int d = colBase + wn * 64 + nt * 16 + l15;
            int part = d >> 10;
            int h = (d >> 6) & 15;
            int hd = d & 63;
            f16* dst = (part == 0) ? Q : (part == 1) ? Kq : V;
            for (int r = 0; r < 4; ++r) {
                int m = m0 + r;
                int b = m >> 11, n = m & 2047;
                dst[(size_t)((b * 16 + h) * 2048 + n) * 64 + hd] = (f16)acc[mt][nt][r];
            }
        }
    }
}

// ---------------- Flash attention: swapped-QK^T 32x32 structure (T12).
// Per (b,h): 128 q-rows/block, 4 waves x 32 q-rows, 64-key tiles.
// S^T = mfma32(K, Q): lane owns P-row (qrow = lane&31), keys crow(r,hi).
// Softmax fully in-register; P -> f16 via cvt_pkrtz + permlane32_swap;
// PV A-operand straight from registers; only V^T staged in LDS (dbuf).
__global__ __launch_bounds__(256, 2)
void attn_kernel(const f16* __restrict__ Q, const f16* __restrict__ Kk,
                 const f16* __restrict__ V, f16* __restrict__ O) {
    const int bh = blockIdx.y;
    const int qt = blockIdx.x;
    const f16* Qb = Q + (size_t)bh * 2048 * 64;
    const f16* Kb = Kk + (size_t)bh * 2048 * 64;
    const f16* Vb = V + (size_t)bh * 2048 * 64;
    int tid = threadIdx.x, lane = tid & 63, wave = tid >> 6;
    int l31 = lane & 31, hi = lane >> 5;

    __shared__ __align__(16) f16 Vt[2][64 * 72];  // V^T [hd][key], dbuf, stride 72

    int qbase = qt * 128 + wave * 32;

    // Q fragments: A/B 32x32x16 layout -> lane holds [l31][hi*8+j]
    half8 aQ[4];
#pragma unroll
    for (int d = 0; d < 4; ++d)
        aQ[d] = *(const half8*)(Qb + (size_t)(qbase + l31) * 64 + d * 16 + hi * 8);

    f32x16 oacc0 = {}, oacc1 = {}, lacc = {};
    float mrow = -1e30f;

    half8 vone;
#pragma unroll
    for (int j = 0; j < 8; ++j) vone[j] = (f16)1.0f;

    // prologue: tile 0 K frags + stage Vt[0]
    half8 bK0[4], bK1[4];
#pragma unroll
    for (int d = 0; d < 4; ++d) {
        bK0[d] = *(const half8*)(Kb + (size_t)(l31) * 64 + d * 16 + hi * 8);
        bK1[d] = *(const half8*)(Kb + (size_t)(32 + l31) * 64 + d * 16 + hi * 8);
    }
    {
        const f16* vsrc = Vb + (size_t)lane * 64 + wave * 16;
        half8 v0 = *(const half8*)(vsrc);
        half8 v1 = *(const half8*)(vsrc + 8);
#pragma unroll
        for (int j = 0; j < 8; ++j) {
            Vt[0][(wave * 16 + j) * 72 + lane] = v0[j];
            Vt[0][(wave * 16 + 8 + j) * 72 + lane] = v1[j];
        }
    }

#pragma unroll 2
    for (int it = 0; it < 32; ++it) {
        int buf = it & 1;
        __syncthreads();  // Vt[buf] staged by all; prior reads of Vt[buf^1] done

        // S^T = K Q^T  (rows = keys, cols = qrows)
        f32x16 s0 = {}, s1 = {};
#pragma unroll
        for (int d = 0; d < 4; ++d) s0 = MFMA32(bK0[d], aQ[d], s0);
#pragma unroll
        for (int d = 0; d < 4; ++d) s1 = MFMA32(bK1[d], aQ[d], s1);

        // prefetch next tile K frags + V rows (hide under softmax + PV)
        half8 bK0n[4], bK1n[4], v0n, v1n;
        if (it < 31) {
            int t1 = (it + 1) * 64;
#pragma unroll
            for (int d = 0; d < 4; ++d) {
                bK0n[d] = *(const half8*)(Kb + (size_t)(t1 + l31) * 64 + d * 16 + hi * 8);
                bK1n[d] = *(const half8*)(Kb + (size_t)(t1 + 32 + l31) * 64 + d * 16 + hi * 8);
            }
            const f16* vsrc = Vb + (size_t)(t1 + lane) * 64 + wave * 16;
            v0n = *(const half8*)(vsrc);
            v1n = *(const half8*)(vsrc + 8);
        }

        // row max: 31 in-register fmax + 1 cross-half shuffle
        float mx = s0[0];
#pragma unroll
        for (int r = 1; r < 16; ++r) mx = fmaxf(mx, s0[r]);
#pragma unroll
        for (int r = 0; r < 16; ++r) mx = fmaxf(mx, s1[r]);
        mx = fmaxf(mx, __shfl_xor(mx, 32, 64));

        // defer-max (THR=8, log2 domain)
        if (__any(mx > mrow + 8.0f)) {
            float mnew = fmaxf(mrow, mx);
            float alpha = exp2f(mrow - mnew);
            mrow = mnew;
#pragma unroll
            for (int r = 0; r < 16; ++r) {
                int cr = (r & 3) + 8 * (r >> 2) + 4 * hi;
                float ar = __shfl(alpha, cr, 64);
                oacc0[r] *= ar;
                oacc1[r] *= ar;
                lacc[r] *= ar;
            }
        }

        // p = exp2(s - m) in place
#pragma unroll
        for (int r = 0; r < 16; ++r) s0[r] = exp2f(s0[r] - mrow);
#pragma unroll
        for (int r = 0; r < 16; ++r) s1[r] = exp2f(s1[r] - mrow);

        // pack P -> A-operand fragments: PA[ks] holds P[qrow][ks*16 + hi*8 + j]
        half8 PA[4];
        {
            union { half8 h; unsigned u[4]; } w;
            // kb=0, kstep0: regs 0..7
            uint2_ r02 = __builtin_amdgcn_permlane32_swap(pkrtz(s0[0], s0[1]), pkrtz(s0[4], s0[5]), false, false);
            uint2_ r13 = __builtin_amdgcn_permlane32_swap(pkrtz(s0[2], s0[3]), pkrtz(s0[6], s0[7]), false, false);
            w.u[0] = r02[0]; w.u[1] = r13[0]; w.u[2] = r02[1]; w.u[3] = r13[1];
            PA[0] = w.h;
            // kb=0, kstep1: regs 8..15
            r02 = __builtin_amdgcn_permlane32_swap(pkrtz(s0[8], s0[9]), pkrtz(s0[12], s0[13]), false, false);
            r13 = __builtin_amdgcn_permlane32_swap(pkrtz(s0[10], s0[11]), pkrtz(s0[14], s0[15]), false, false);
            w.u[0] = r02[0]; w.u[1] = r13[0]; w.u[2] = r02[1]; w.u[3] = r13[1];
            PA[1] = w.h;
            // kb=1, kstep2
            r02 = __builtin_amdgcn_permlane32_swap(pkrtz(s1[0], s1[1]), pkrtz(s1[4], s1[5]), false, false);
            r13 = __builtin_amdgcn_permlane32_swap(pkrtz(s1[2], s1[3]), pkrtz(s1[6], s1[7]), false, false);
            w.u[0] = r02[0]; w.u[1] = r13[0]; w.u[2] = r02[1]; w.u[3] = r13[1];
            PA[2] = w.h;
            // kb=1, kstep3
            r02 = __builtin_amdgcn_permlane32_swap(pkrtz(s1[8], s1[9]), pkrtz(s1[12], s1[13]), false, false);
            r13 = __builtin_amdgcn_permlane32_swap(pkrtz(s1[10], s1[11]), pkrtz(s1[14], s1[15]), false, false);
            w.u[0] = r02[0]; w.u[1] = r13[0]; w.u[2] = r02[1]; w.u[3] = r13[1];
            PA[3] = w.h;
        }

        // O^ += P V ; l += P 1   (B-operand V[key][hd] from Vt: 8 keys @ fixed hd)
#pragma unroll
        for (int ks = 0; ks < 4; ++ks) {
            half8 vf0 = *(const half8*)&Vt[buf][(l31) * 72 + ks * 16 + hi * 8];
            half8 vf1 = *(const half8*)&Vt[buf][(32 + l31) * 72 + ks * 16 + hi * 8];
            oacc0 = MFMA32(PA[ks], vf0, oacc0);
            oacc1 = MFMA32(PA[ks], vf1, oacc1);
            lacc = MFMA32(PA[ks], vone, lacc);
        }

        // stage next Vt; rotate K frags
        if (it < 31) {
#pragma unroll
            for (int j = 0; j < 8; ++j) {
                Vt[buf ^ 1][(wave * 16 + j) * 72 + lane] = v0n[j];
                Vt[buf ^ 1][(wave * 16 + 8 + j) * 72 + lane] = v1n[j];
            }
#pragma unroll
            for (int d = 0; d < 4; ++d) {
                bK0[d] = bK0n[d];
                bK1[d] = bK1n[d];
            }
        }
    }

    // epilogue: O / l -> attn_out [B,N,C] fp16
    // oacc rows: qrow = qbase + (r&3)+8*(r>>2)+4*hi ; cols: hd = hb*32 + l31
    int b = bh >> 4, h = bh & 15;
#pragma unroll
    for (int r = 0; r < 16; ++r) {
        int cr = (r & 3) + 8 * (r >> 2) + 4 * hi;
        int n = qbase + cr;
        float inv = 1.0f / lacc[r];
        O[(size_t)(b * 2048 + n) * 1024 + h * 64 + l31] = (f16)(oacc0[r] * inv);
        O[(size_t)(b * 2048 + n) * 1024 + h * 64 + 32 + l31] = (f16)(oacc1[r] * inv);
    }
}

// ---------------- Proj GEMM: [8192,1024] x [1024,1024]^T + bias -> fp32 out
__global__ __launch_bounds__(256, 2)
void proj_gemm(const f16* __restrict__ A, const f16* __restrict__ W,
               const float* __restrict__ bias, float* __restrict__ out) {
    const int K = 1024;
    __shared__ __align__(16) f16 sA[128 * 64];
    __shared__ __align__(16) f16 sB[128 * 64];
    int tid = threadIdx.x;
    int lane = tid & 63, wave = tid >> 6;
    int wm = wave >> 1, wn = wave & 1;
    int l15 = lane & 15, quad = lane >> 4;
    int rowBase = blockIdx.y * 128;
    int colBase = blockIdx.x * 128;

    float4_ acc[4][4] = {};

    for (int k0 = 0; k0 < K; k0 += 64) {
        for (int i = 0; i < 4; ++i) {
            int seg = wave * 4 + i;
            int e = (seg * 64 + lane) * 8;
            int r = e >> 6, c = e & 63;
            gld_lds16(A + (size_t)(rowBase + r) * K + k0 + c, sA + seg * 512);
            gld_lds16(W + (size_t)(colBase + r) * K + k0 + c, sB + seg * 512);
        }
        __syncthreads();
        for (int ks = 0; ks < 2; ++ks) {
            half8 a[4], b[4];
            for (int mt = 0; mt < 4; ++mt)
                a[mt] = *(const half8*)&sA[(wm * 64 + mt * 16 + l15) * 64 + ks * 32 + quad * 8];
            for (int nt = 0; nt < 4; ++nt)
                b[nt] = *(const half8*)&sB[(wn * 64 + nt * 16 + l15) * 64 + ks * 32 + quad * 8];
            for (int mt = 0; mt < 4; ++mt)
                for (int nt = 0; nt < 4; ++nt)
                    acc[mt][nt] = MFMA16(a[mt], b[nt], acc[mt][nt]);
        }
        __syncthreads();
    }

    for (int mt = 0; mt < 4; ++mt) {
        int m0 = rowBase + wm * 64 + mt * 16 + quad * 4;
        for (int nt = 0; nt < 4; ++nt) {
            int d = colBase + wn * 64 + nt * 16 + l15;
            float bv = bias[d];
            for (int r = 0; r < 4; ++r) {
                int m = m0 + r;
                out[(size_t)m * 1024 + d] = acc[mt][nt][r] + bv;
            }
        }
    }
}

extern "C" void kernel_launch(void* const* d_in, const int* in_sizes, int n_in,
                              void* d_out, int out_size, void* d_ws, size_t ws_size,
                              hipStream_t stream) {
    const float* x     = (const float*)d_in[0];
    const float* Wqkv  = (const float*)d_in[1];
    const float* Wproj = (const float*)d_in[2];
    const float* bproj = (const float*)d_in[3];
    float* out = (float*)d_out;

    f16* ws     = (f16*)d_ws;
    f16* xb     = ws;                    // 8388608
    f16* wqkvb  = xb + 8388608;          // 3145728
    f16* wprojb = wqkvb + 3145728;       // 1048576
    f16* q      = wprojb + 1048576;      // 8388608  [B,H,N,64]
    f16* k      = q + 8388608;           // 8388608
    f16* v      = k + 8388608;           // 8388608
    f16* ao     = v + 8388608;           // 8388608  [B,N,C]

    // qkv scale: 1/sqrt(64) * log2(e) folded into Q rows of W_qkv
    const float qscale = 0.125f * 1.4426950408889634f;

    cast_kernel<<<8192, 256, 0, stream>>>(x, xb, 8388608, 0, 1.f);
    cast_kernel<<<3072, 256, 0, stream>>>(Wqkv, wqkvb, 3145728, 1048576, qscale);
    cast_kernel<<<1024, 256, 0, stream>>>(Wproj, wprojb, 1048576, 0, 1.f);

    qkv_gemm<<<dim3(24, 64), 256, 0, stream>>>(xb, wqkvb, q, k, v);
    attn_kernel<<<dim3(16, 64), 256, 0, stream>>>(q, k, v, ao);
    proj_gemm<<<dim3(8, 64), 256, 0, stream>>>(ao, wprojb, bproj, out);
}